// Round 14
// baseline (259.924 us; speedup 1.0000x reference)
//
#include <hip/hip_runtime.h>
#include <hip/hip_bf16.h>

#define N_PTS   40000
#define N_B     2
#define N_P     128
#define N_K     32
#define N_KC    4
#define N_FEAT  128
#define NQ2     (N_B * N_P * N_K)   // 8192
#define BIGF    3.0e38f

#define NSEG    125                 // knn2 segments
#define SEGSZ   (N_PTS / NSEG)      // 320
#define QPT     4                   // queries per thread in knn2
#define K2THR   256
#define K2TILES (NQ2 / (K2THR * QPT))  // 8

#define K1SUB   8                   // knn1 scan sub-ranges per query
#define K1RANGE (N_PTS / K1SUB)     // 5000
#define QCAP1   1024                // knn1 per-query candidate cap (E[n]=341)

#define QCAP    96                  // knn2 per-query candidate cap (E[n]=42)

// knn2 tau: (2.2*r4)^2 ; knn1 tau: (2.2*r32)^2, r32=(3*32/(4pi*40000))^(1/3)
#define TAU2    4.0e-3f
#define TAU1    1.6e-2f

// Scratch in module __device__ globals (d_ws unusable: ws too small, R1-R3).
__device__ int    g_sidx[N_P];
__device__ int    g_fidx[NQ2];
__device__ int    g_q1cnt[256];                               // knn1 per-query counts
__device__ unsigned long long g_q1list[256 * QCAP1];          // 2 MB knn1 candidates
__device__ int    g_fb1count;
__device__ int    g_fb1list[256];
__device__ int    g_qcnt[NQ2];                                // knn2 per-query counts
__device__ float2 g_qlist[(size_t)NQ2 * QCAP];                // 6.3 MB knn2 candidates
__device__ float  g_lpart[256];    // [0..63] loss (direct), [128..159] fallback (atomic)
__device__ float  g_M3[9];
__device__ float  g_WxS[9];
__device__ int    g_fcount;
__device__ int    g_flist[NQ2];

__device__ __forceinline__ int clampi(int v, int lo, int hi) { return v < lo ? lo : (v > hi ? hi : v); }

// ---------------------------------------------------------------------------
// Prep: decode sampled_idx (auto-detect), M3 = Wf@Wc, stage Wx, zero all
// counters/slots.
// ---------------------------------------------------------------------------
__global__ __launch_bounds__(128) void prep_kernel(
    const void* __restrict__ sidx_raw,
    const float* __restrict__ Wf,
    const float* __restrict__ Wx,
    const float* __restrict__ Wc)
{
    __shared__ int ok32_s, odd0_s, ok64_s, okf32_s;
    const int tid = threadIdx.x;
    if (tid == 0) { ok32_s = 1; odd0_s = 1; ok64_s = 1; okf32_s = 1; g_fcount = 0; g_fb1count = 0; }
    g_lpart[tid] = 0.0f;
    g_lpart[128 + tid] = 0.0f;
    for (int i = tid; i < NQ2; i += 128) g_qcnt[i] = 0;
    for (int i = tid; i < 256; i += 128) g_q1cnt[i] = 0;
    if (tid < 9) {
        const int d = tid / 3, e = tid % 3;
        float acc = 0.0f;
        for (int f0 = 0; f0 < N_FEAT; ++f0)
            acc += Wf[d * N_FEAT + f0] * Wc[f0 * 3 + e];
        g_M3[tid]  = acc;
        g_WxS[tid] = Wx[tid];
    }
    __syncthreads();

    const int*       p32 = (const int*)sidx_raw;
    const long long* p64 = (const long long*)sidx_raw;
    const float*     pf  = (const float*)sidx_raw;

    const int       v32 = p32[tid];
    const long long v64 = p64[tid];
    const float     vf  = pf[tid];

    if (!(v32 >= 0 && v32 < N_PTS)) atomicAnd(&ok32_s, 0);
    if ((tid & 1) && v32 != 0)      atomicAnd(&odd0_s, 0);
    if (!(v64 >= 0 && v64 < N_PTS)) atomicAnd(&ok64_s, 0);
    if (!(vf >= 0.0f && vf < (float)N_PTS && vf == floorf(vf))) atomicAnd(&okf32_s, 0);
    __syncthreads();

    int si;
    if (ok32_s && !(odd0_s && ok64_s)) si = v32;
    else if (ok64_s)                   si = (int)v64;
    else if (okf32_s)                  si = (int)(vf + 0.5f);
    else                               si = 0;
    g_sidx[tid] = clampi(si, 0, N_PTS - 1);
}

// ---------------------------------------------------------------------------
// KNN1 scan v3: tau-append (no per-lane top-k, no sort — R13's 2048-key
// bitonic was 80% of the 95us kernel). Grid (256 q, 8 sub) = 2048 blocks.
// Keys (d2_bits<<32)|idx are unique => later sort is canonical regardless
// of nondeterministic append order.
// ---------------------------------------------------------------------------
__global__ __launch_bounds__(256) void knn1_scan_kernel(
    const float* __restrict__ noisy)
{
    const int qb  = blockIdx.x;        // 0..255
    const int sub = blockIdx.y;        // 0..7
    const int b   = qb >> 7;
    const int p   = qb & 127;
    const int tid = threadIdx.x;
    const float* nb = noisy + b * (N_PTS * 3);

    const int si = g_sidx[p];
    const float qx = nb[si * 3 + 0];
    const float qy = nb[si * 3 + 1];
    const float qz = nb[si * 3 + 2];

    const int jbeg = sub * K1RANGE;
    const int jend = jbeg + K1RANGE;
    for (int j = jbeg + tid; j < jend; j += 256) {
        const float dx = qx - nb[j * 3 + 0];
        const float dy = qy - nb[j * 3 + 1];
        const float dz = qz - nb[j * 3 + 2];
        const float d2 = fmaf(dz, dz, fmaf(dy, dy, dx * dx));
        if (d2 < TAU1) {
            const int slot = atomicAdd(&g_q1cnt[qb], 1);
            if (slot < QCAP1)
                g_q1list[qb * QCAP1 + slot] =
                    ((unsigned long long)__float_as_uint(d2) << 32) | (unsigned int)j;
        }
    }
}

// ---------------------------------------------------------------------------
// KNN1 merge v3: 256 blocks x 256 thr. Bitonic-sort <=1024 keys (padded with
// ~0), first 32 = exact stable top-32. cnt<32 or cnt>QCAP1 -> fb list.
// Pair-indexed CE mapping: every thread does useful work (2 CE/substage).
// ---------------------------------------------------------------------------
__global__ __launch_bounds__(256) void knn1_merge_kernel()
{
    __shared__ unsigned long long keys[QCAP1];   // 8 KB
    const int qb  = blockIdx.x;
    const int tid = threadIdx.x;
    const int cnt = g_q1cnt[qb];

    if (cnt < 32 || cnt > QCAP1) {
        if (tid == 0) {
            const int slot = atomicAdd(&g_fb1count, 1);
            g_fb1list[slot] = qb;
        }
        return;
    }

    for (int i = tid; i < QCAP1; i += 256)
        keys[i] = (i < cnt) ? g_q1list[qb * QCAP1 + i] : ~0ULL;
    __syncthreads();

    for (int k = 2; k <= QCAP1; k <<= 1) {
        for (int jj = k >> 1; jj > 0; jj >>= 1) {
            for (int idx = tid; idx < QCAP1 / 2; idx += 256) {
                const int i = ((idx & ~(jj - 1)) << 1) | (idx & (jj - 1));
                const int partner = i | jj;
                const bool asc = ((i & k) == 0);
                const unsigned long long a = keys[i];
                const unsigned long long c = keys[partner];
                if ((a > c) == asc) { keys[i] = c; keys[partner] = a; }
            }
            __syncthreads();
        }
    }

    if (tid < 32) {
        const int idx = (int)(keys[tid] & 0xFFFFFFFFull);
        g_fidx[qb * 32 + tid] = clampi(idx, 0, N_PTS - 1);
    }
}

// ---------------------------------------------------------------------------
// KNN1 exact fallback (R12's proven full scan + 2048-sort), only for flagged
// queries (corner shortfall / overflow; expect ~0). ~instant when count==0.
// ---------------------------------------------------------------------------
__global__ __launch_bounds__(256) void knn1_fb_kernel(
    const float* __restrict__ noisy)
{
    const int tid = threadIdx.x;
    const int count = g_fb1count;

    for (int qi = blockIdx.x; qi < count; qi += gridDim.x) {
        const int qb = g_fb1list[qi];
        const int b  = qb >> 7;
        const int p  = qb & 127;
        const float* nb = noisy + b * (N_PTS * 3);

        const int si = g_sidx[p];
        const float qx = nb[si * 3 + 0];
        const float qy = nb[si * 3 + 1];
        const float qz = nb[si * 3 + 2];

        float bd[8]; int bi[8];
#pragma unroll
        for (int i = 0; i < 8; ++i) { bd[i] = BIGF; bi[i] = 0x7fffffff; }

        for (int j = tid; j < N_PTS; j += 256) {
            const float dx = qx - nb[j * 3 + 0];
            const float dy = qy - nb[j * 3 + 1];
            const float dz = qz - nb[j * 3 + 2];
            const float d2 = fmaf(dz, dz, fmaf(dy, dy, dx * dx));
            if (d2 < bd[7]) {
                bd[7] = d2; bi[7] = j;
#pragma unroll
                for (int t = 7; t > 0; --t) {
                    if (bd[t] < bd[t - 1]) {
                        float td = bd[t]; bd[t] = bd[t - 1]; bd[t - 1] = td;
                        int   ti = bi[t]; bi[t] = bi[t - 1]; bi[t - 1] = ti;
                    }
                }
            }
        }

        __shared__ unsigned long long keys[2048];   // 16 KB
#pragma unroll
        for (int t = 0; t < 8; ++t) {
            keys[tid * 8 + t] = ((unsigned long long)__float_as_uint(bd[t]) << 32)
                              | (unsigned int)bi[t];
        }
        __syncthreads();

        for (int k = 2; k <= 2048; k <<= 1) {
            for (int jj = k >> 1; jj > 0; jj >>= 1) {
#pragma unroll
                for (int base = 0; base < 2048; base += 256) {
                    const int i = base + tid;
                    const int partner = i ^ jj;
                    if (partner > i) {
                        const bool asc = ((i & k) == 0);
                        const unsigned long long a = keys[i];
                        const unsigned long long c = keys[partner];
                        if ((a > c) == asc) { keys[i] = c; keys[partner] = a; }
                    }
                }
                __syncthreads();
            }
        }

        if (tid < 32) {
            const int idx = (int)(keys[tid] & 0xFFFFFFFFull);
            g_fidx[qb * 32 + tid] = clampi(idx, 0, N_PTS - 1);
        }
        __syncthreads();
    }
}

// ---------------------------------------------------------------------------
// KNN2 (unchanged from R13): QPT=4, grid 8x125, tau-append compact lists.
// ---------------------------------------------------------------------------
__global__ __launch_bounds__(K2THR) void knn2_seg_kernel(
    const float* __restrict__ noisy,
    const float* __restrict__ clean)
{
    __shared__ float4 pts[SEGSZ];   // 5 KB
    const int tile = blockIdx.x;    // 0..7
    const int seg  = blockIdx.y;    // 0..124
    const int tid  = threadIdx.x;
    const int g0   = tile * (K2THR * QPT) + tid * QPT;
    const int b    = g0 >> 12;
    const float* cb = clean + b * (N_PTS * 3);
    const float* nb = noisy + b * (N_PTS * 3);

    const int base = seg * SEGSZ;
    for (int i = tid; i < SEGSZ; i += K2THR) {
        const int j = base + i;
        const float px = cb[j * 3 + 0], py = cb[j * 3 + 1], pz = cb[j * 3 + 2];
        const float pp = fmaf(pz, pz, fmaf(py, py, px * px));
        pts[i] = make_float4(px, py, pz, pp);
    }

    float fm2x[QPT], fm2y[QPT], fm2z[QPT];
    float bd0[QPT], bd1[QPT], bd2[QPT], bd3[QPT];
    int   bi0[QPT], bi1[QPT], bi2[QPT], bi3[QPT];
#pragma unroll
    for (int qq = 0; qq < QPT; ++qq) {
        const int fid = clampi(g_fidx[g0 + qq], 0, N_PTS - 1);
        const float fx = nb[fid * 3 + 0];
        const float fy = nb[fid * 3 + 1];
        const float fz = nb[fid * 3 + 2];
        fm2x[qq] = -2.0f * fx; fm2y[qq] = -2.0f * fy; fm2z[qq] = -2.0f * fz;
        const float ff = fmaf(fz, fz, fmaf(fy, fy, fx * fx));
        const float tau_p = TAU2 - ff;   // partial-space threshold
        bd0[qq] = tau_p; bd1[qq] = tau_p; bd2[qq] = tau_p; bd3[qq] = tau_p;
        bi0[qq] = -1;    bi1[qq] = -1;    bi2[qq] = -1;    bi3[qq] = -1;
    }

    __syncthreads();

#pragma unroll 2
    for (int j = 0; j < SEGSZ; ++j) {
        const float4 pp = pts[j];
#pragma unroll
        for (int qq = 0; qq < QPT; ++qq) {
            const float d2 = fmaf(fm2x[qq], pp.x, fmaf(fm2y[qq], pp.y, fmaf(fm2z[qq], pp.z, pp.w)));
            if (d2 < bd3[qq]) {
                bd3[qq] = d2; bi3[qq] = base + j;
                if (bd3[qq] < bd2[qq]) { float t = bd2[qq]; bd2[qq] = bd3[qq]; bd3[qq] = t; int ti = bi2[qq]; bi2[qq] = bi3[qq]; bi3[qq] = ti; }
                if (bd2[qq] < bd1[qq]) { float t = bd1[qq]; bd1[qq] = bd2[qq]; bd2[qq] = t; int ti = bi1[qq]; bi1[qq] = bi2[qq]; bi2[qq] = ti; }
                if (bd1[qq] < bd0[qq]) { float t = bd0[qq]; bd0[qq] = bd1[qq]; bd1[qq] = t; int ti = bi0[qq]; bi0[qq] = bi1[qq]; bi1[qq] = ti; }
            }
        }
    }

#pragma unroll
    for (int qq = 0; qq < QPT; ++qq) {
        const int g = g0 + qq;
        const float bds[4] = { bd0[qq], bd1[qq], bd2[qq], bd3[qq] };
        const int   bis[4] = { bi0[qq], bi1[qq], bi2[qq], bi3[qq] };
#pragma unroll
        for (int t = 0; t < 4; ++t) {
            if (bis[t] >= 0) {
                const int slot = atomicAdd(&g_qcnt[g], 1);
                if (slot < QCAP) g_qlist[(size_t)g * QCAP + slot] = make_float2(bds[t], __int_as_float(bis[t]));
            }
        }
    }
}

// ---------------------------------------------------------------------------
// Merge per-query knn2 list + epilogue (unchanged from R13).
// ---------------------------------------------------------------------------
__global__ __launch_bounds__(128) void loss_kernel(
    const float* __restrict__ noisy,
    const float* __restrict__ clean)
{
    __shared__ float red[2];
    const int tid = threadIdx.x;
    const int g = blockIdx.x * 128 + tid;    // 64 blocks x 128
    const int b = g >> 12;
    const int p = (g >> 5) & 127;
    const float* nb = noisy + b * (N_PTS * 3);
    const float* cb = clean + b * (N_PTS * 3);

    const int si = g_sidx[p];
    const float qx = nb[si * 3 + 0], qy = nb[si * 3 + 1], qz = nb[si * 3 + 2];
    const int fid = clampi(g_fidx[g], 0, N_PTS - 1);
    const float fx = nb[fid * 3 + 0], fy = nb[fid * 3 + 1], fz = nb[fid * 3 + 2];

    const int cnt = g_qcnt[g];
    float t2 = 0.0f;

    if (cnt < 4 || cnt > QCAP) {
        const int slot = atomicAdd(&g_fcount, 1);
        g_flist[slot] = g;
    } else {
        float bd0 = BIGF, bd1 = BIGF, bd2 = BIGF, bd3 = BIGF;
        int   bi0 = 0x7fffffff, bi1 = 0x7fffffff, bi2 = 0x7fffffff, bi3 = 0x7fffffff;
        const float2* lst = g_qlist + (size_t)g * QCAP;
        for (int t = 0; t < cnt; ++t) {
            const float2 e = lst[t];
            const float d2 = e.x;
            const int  idx = __float_as_int(e.y);
            if (d2 < bd3 || (d2 == bd3 && idx < bi3)) {
                bd3 = d2; bi3 = idx;
                if (bd3 < bd2 || (bd3 == bd2 && bi3 < bi2)) { float q0 = bd2; bd2 = bd3; bd3 = q0; int ti = bi2; bi2 = bi3; bi3 = ti; }
                if (bd2 < bd1 || (bd2 == bd1 && bi2 < bi1)) { float q0 = bd1; bd1 = bd2; bd2 = q0; int ti = bi1; bi1 = bi2; bi2 = ti; }
                if (bd1 < bd0 || (bd1 == bd0 && bi1 < bi0)) { float q0 = bd0; bd0 = bd1; bd1 = q0; int ti = bi0; bi0 = bi1; bi1 = ti; }
            }
        }

        const float mx = 0.25f * (cb[bi0*3+0] + cb[bi1*3+0] + cb[bi2*3+0] + cb[bi3*3+0]);
        const float my = 0.25f * (cb[bi0*3+1] + cb[bi1*3+1] + cb[bi2*3+1] + cb[bi3*3+1]);
        const float mz = 0.25f * (cb[bi0*3+2] + cb[bi1*3+2] + cb[bi2*3+2] + cb[bi3*3+2]);

        const float gx = mx - fx, gy = my - fy, gz = mz - fz;
        const float rx = fx - qx, ry = fy - qy, rz = fz - qz;
        const float ex = rx * g_WxS[0] + ry * g_WxS[3] + rz * g_WxS[6] + qx * g_M3[0] + qy * g_M3[3] + qz * g_M3[6];
        const float ey = rx * g_WxS[1] + ry * g_WxS[4] + rz * g_WxS[7] + qx * g_M3[1] + qy * g_M3[4] + qz * g_M3[7];
        const float ez = rx * g_WxS[2] + ry * g_WxS[5] + rz * g_WxS[8] + qx * g_M3[2] + qy * g_M3[5] + qz * g_M3[8];
        const float dx = ex - gx, dy = ey - gy, dz = ez - gz;
        t2 = dx * dx + dy * dy + dz * dz;
    }

#pragma unroll
    for (int off = 32; off; off >>= 1) t2 += __shfl_down(t2, off);
    if ((tid & 63) == 0) red[tid >> 6] = t2;
    __syncthreads();
    if (tid == 0) g_lpart[blockIdx.x] = red[0] + red[1];
}

// ---------------------------------------------------------------------------
// KNN2 exact fallback (unchanged from R13).
// ---------------------------------------------------------------------------
__global__ __launch_bounds__(64) void fallback_kernel(
    const float* __restrict__ noisy,
    const float* __restrict__ clean)
{
    const int lane  = threadIdx.x;
    const int count = g_fcount;

    for (int qi = blockIdx.x; qi < count; qi += gridDim.x) {
        const int g = g_flist[qi];
        const int b = g >> 12;
        const int p = (g >> 5) & 127;
        const float* nb = noisy + b * (N_PTS * 3);
        const float* cb = clean + b * (N_PTS * 3);

        const int fid = clampi(g_fidx[g], 0, N_PTS - 1);
        const float fx = nb[fid * 3 + 0], fy = nb[fid * 3 + 1], fz = nb[fid * 3 + 2];

        float bd[4]; int bi[4];
#pragma unroll
        for (int t = 0; t < 4; ++t) { bd[t] = BIGF; bi[t] = 0x7fffffff; }

        for (int j = lane; j < N_PTS; j += 64) {
            const float dx = fx - cb[j * 3 + 0];
            const float dy = fy - cb[j * 3 + 1];
            const float dz = fz - cb[j * 3 + 2];
            const float d2 = fmaf(dz, dz, fmaf(dy, dy, dx * dx));
            if (d2 < bd[3]) {
                bd[3] = d2; bi[3] = j;
#pragma unroll
                for (int t = 3; t > 0; --t) {
                    if (bd[t] < bd[t - 1]) {
                        float td = bd[t]; bd[t] = bd[t - 1]; bd[t - 1] = td;
                        int   ti = bi[t]; bi[t] = bi[t - 1]; bi[t - 1] = ti;
                    }
                }
            }
        }

        int nn[4];
        int cur = 0;
        for (int r = 0; r < 4; ++r) {
            float v  = (cur < 4) ? bd[cur] : BIGF;
            int   vi = (cur < 4) ? bi[cur] : 0x7fffffff;
            int   who = lane;
#pragma unroll
            for (int off = 32; off; off >>= 1) {
                const float v2  = __shfl_down(v, off);
                const int   vi2 = __shfl_down(vi, off);
                const int   w2  = __shfl_down(who, off);
                if (v2 < v || (v2 == v && vi2 < vi)) { v = v2; vi = vi2; who = w2; }
            }
            const int bvi = __shfl(vi, 0);
            const int bwh = __shfl(who, 0);
            nn[r] = bvi;
            if (lane == bwh) cur++;
        }

        if (lane == 0) {
            const int si = g_sidx[p];
            const float qx = nb[si * 3 + 0], qy = nb[si * 3 + 1], qz = nb[si * 3 + 2];
            const int n0 = clampi(nn[0],0,N_PTS-1), n1 = clampi(nn[1],0,N_PTS-1);
            const int n2 = clampi(nn[2],0,N_PTS-1), n3 = clampi(nn[3],0,N_PTS-1);
            const float mx = 0.25f * (cb[n0*3+0] + cb[n1*3+0] + cb[n2*3+0] + cb[n3*3+0]);
            const float my = 0.25f * (cb[n0*3+1] + cb[n1*3+1] + cb[n2*3+1] + cb[n3*3+1]);
            const float mz = 0.25f * (cb[n0*3+2] + cb[n1*3+2] + cb[n2*3+2] + cb[n3*3+2]);
            const float gx = mx - fx, gy = my - fy, gz = mz - fz;
            const float rx = fx - qx, ry = fy - qy, rz = fz - qz;
            const float ex = rx * g_WxS[0] + ry * g_WxS[3] + rz * g_WxS[6] + qx * g_M3[0] + qy * g_M3[3] + qz * g_M3[6];
            const float ey = rx * g_WxS[1] + ry * g_WxS[4] + rz * g_WxS[7] + qx * g_M3[1] + qy * g_M3[4] + qz * g_M3[7];
            const float ez = rx * g_WxS[2] + ry * g_WxS[5] + rz * g_WxS[8] + qx * g_M3[2] + qy * g_M3[5] + qz * g_M3[8];
            const float dx = ex - gx, dy = ey - gy, dz = ez - gz;
            atomicAdd(&g_lpart[128 + blockIdx.x], dx * dx + dy * dy + dz * dz);
        }
    }
}

__global__ void final_kernel(float* __restrict__ out)
{
    const int tid = threadIdx.x;    // 64
    float v = (g_lpart[tid] + g_lpart[64 + tid]) + (g_lpart[128 + tid] + g_lpart[192 + tid]);
#pragma unroll
    for (int off = 32; off; off >>= 1) v += __shfl_down(v, off);
    if (tid == 0) out[0] = v * (50.0f / 8192.0f);   // 0.5 * (1/SIGMA) / 8192
}

extern "C" void kernel_launch(void* const* d_in, const int* in_sizes, int n_in,
                              void* d_out, int out_size, void* d_ws, size_t ws_size,
                              hipStream_t stream)
{
    (void)d_ws; (void)ws_size; (void)in_sizes; (void)n_in; (void)out_size;

    const float* noisy = (const float*)d_in[0];
    const float* clean = (const float*)d_in[1];
    const float* Wf    = (const float*)d_in[3];
    const float* Wx    = (const float*)d_in[4];
    const float* Wc    = (const float*)d_in[5];

    prep_kernel<<<1, 128, 0, stream>>>(d_in[2], Wf, Wx, Wc);
    knn1_scan_kernel<<<dim3(256, K1SUB), 256, 0, stream>>>(noisy);
    knn1_merge_kernel<<<256, 256, 0, stream>>>();
    knn1_fb_kernel<<<64, 256, 0, stream>>>(noisy);
    knn2_seg_kernel<<<dim3(K2TILES, NSEG), K2THR, 0, stream>>>(noisy, clean);
    loss_kernel<<<64, 128, 0, stream>>>(noisy, clean);
    fallback_kernel<<<32, 64, 0, stream>>>(noisy, clean);
    final_kernel<<<1, 64, 0, stream>>>((float*)d_out);
}

// Round 15
// 197.325 us; speedup vs baseline: 1.3172x; 1.3172x over previous
//
#include <hip/hip_runtime.h>
#include <hip/hip_bf16.h>

#define N_PTS   40000
#define N_B     2
#define N_P     128
#define N_K     32
#define N_KC    4
#define N_FEAT  128
#define NQ2     (N_B * N_P * N_K)   // 8192
#define BIGF    3.0e38f

#define NSEG    125                 // knn2 segments
#define SEGSZ   (N_PTS / NSEG)      // 320
#define QPT     4                   // queries per thread in knn2
#define K2THR   256
#define K2TILES (NQ2 / (K2THR * QPT))  // 8

#define K1SUB   8                   // knn1 scan sub-ranges per query
#define K1RANGE (N_PTS / K1SUB)     // 5000
#define QCAP1   1024                // knn1 per-query candidate cap (E[n]=341)
#define LBUF1   320                 // knn1 per-block LDS buffer (E=43, P(>320)~0)

#define QCAP    96                  // knn2 per-query candidate cap (E[n]=42)

// knn2 tau: (2.2*r4)^2 ; knn1 tau: (2.2*r32)^2
#define TAU2    4.0e-3f
#define TAU1    1.6e-2f

// Scratch in module __device__ globals (d_ws unusable: ws too small, R1-R3).
__device__ int    g_sidx[N_P];
__device__ int    g_fidx[NQ2];
__device__ int    g_q1cnt[256];                               // knn1 per-query counts
__device__ unsigned long long g_q1list[256 * QCAP1];          // 2 MB knn1 candidates
__device__ int    g_fb1count;
__device__ int    g_fb1list[256];
__device__ int    g_qcnt[NQ2];                                // knn2 per-query counts
__device__ float2 g_qlist[(size_t)NQ2 * QCAP];                // 6.3 MB knn2 candidates
__device__ float  g_lpart[256];    // [0..63] loss (direct), [128..159] fallback (atomic)
__device__ float  g_M3[9];
__device__ float  g_WxS[9];
__device__ int    g_fcount;
__device__ int    g_flist[NQ2];

__device__ __forceinline__ int clampi(int v, int lo, int hi) { return v < lo ? lo : (v > hi ? hi : v); }

// ---------------------------------------------------------------------------
// Prep: decode sampled_idx (auto-detect), M3 = Wf@Wc, stage Wx, zero all
// counters/slots.
// ---------------------------------------------------------------------------
__global__ __launch_bounds__(128) void prep_kernel(
    const void* __restrict__ sidx_raw,
    const float* __restrict__ Wf,
    const float* __restrict__ Wx,
    const float* __restrict__ Wc)
{
    __shared__ int ok32_s, odd0_s, ok64_s, okf32_s;
    const int tid = threadIdx.x;
    if (tid == 0) { ok32_s = 1; odd0_s = 1; ok64_s = 1; okf32_s = 1; g_fcount = 0; g_fb1count = 0; }
    g_lpart[tid] = 0.0f;
    g_lpart[128 + tid] = 0.0f;
    for (int i = tid; i < NQ2; i += 128) g_qcnt[i] = 0;
    for (int i = tid; i < 256; i += 128) g_q1cnt[i] = 0;
    if (tid < 9) {
        const int d = tid / 3, e = tid % 3;
        float acc = 0.0f;
        for (int f0 = 0; f0 < N_FEAT; ++f0)
            acc += Wf[d * N_FEAT + f0] * Wc[f0 * 3 + e];
        g_M3[tid]  = acc;
        g_WxS[tid] = Wx[tid];
    }
    __syncthreads();

    const int*       p32 = (const int*)sidx_raw;
    const long long* p64 = (const long long*)sidx_raw;
    const float*     pf  = (const float*)sidx_raw;

    const int       v32 = p32[tid];
    const long long v64 = p64[tid];
    const float     vf  = pf[tid];

    if (!(v32 >= 0 && v32 < N_PTS)) atomicAnd(&ok32_s, 0);
    if ((tid & 1) && v32 != 0)      atomicAnd(&odd0_s, 0);
    if (!(v64 >= 0 && v64 < N_PTS)) atomicAnd(&ok64_s, 0);
    if (!(vf >= 0.0f && vf < (float)N_PTS && vf == floorf(vf))) atomicAnd(&okf32_s, 0);
    __syncthreads();

    int si;
    if (ok32_s && !(odd0_s && ok64_s)) si = v32;
    else if (ok64_s)                   si = (int)v64;
    else if (okf32_s)                  si = (int)(vf + 0.5f);
    else                               si = 0;
    g_sidx[tid] = clampi(si, 0, N_PTS - 1);
}

// ---------------------------------------------------------------------------
// KNN1 scan v4: tau-append with BLOCK-LOCAL LDS buffering. R14's per-hit
// global atomicAdd on 256 packed counters serialized on 16 cache lines
// (VALUBusy 5%, 95% stall). Now: LDS atomics for slots (block-local,
// ~30cyc), ONE global atomicAdd per block to reserve a range, bulk flush.
// Global atomics: 87k -> 2048. LDS overflow (impossible-ish) forces the
// exact-fb path by pushing cnt past QCAP1.
// ---------------------------------------------------------------------------
__global__ __launch_bounds__(256) void knn1_scan_kernel(
    const float* __restrict__ noisy)
{
    __shared__ unsigned long long buf[LBUF1];   // 2.5 KB
    __shared__ int lcnt;
    __shared__ int base_s;
    const int qb  = blockIdx.x;        // 0..255
    const int sub = blockIdx.y;        // 0..7
    const int b   = qb >> 7;
    const int p   = qb & 127;
    const int tid = threadIdx.x;
    const float* nb = noisy + b * (N_PTS * 3);

    if (tid == 0) lcnt = 0;
    const int si = g_sidx[p];
    const float qx = nb[si * 3 + 0];
    const float qy = nb[si * 3 + 1];
    const float qz = nb[si * 3 + 2];
    __syncthreads();

    const int jbeg = sub * K1RANGE;
    const int jend = jbeg + K1RANGE;
    for (int j = jbeg + tid; j < jend; j += 256) {
        const float dx = qx - nb[j * 3 + 0];
        const float dy = qy - nb[j * 3 + 1];
        const float dz = qz - nb[j * 3 + 2];
        const float d2 = fmaf(dz, dz, fmaf(dy, dy, dx * dx));
        if (d2 < TAU1) {
            const int slot = atomicAdd(&lcnt, 1);   // LDS atomic
            if (slot < LBUF1)
                buf[slot] = ((unsigned long long)__float_as_uint(d2) << 32) | (unsigned int)j;
        }
    }
    __syncthreads();

    const int cnt = lcnt;
    if (tid == 0) {
        // overflow -> force cnt>QCAP1 so merge routes this query to exact fb
        const int add = (cnt <= LBUF1) ? cnt : (QCAP1 + 1000);
        base_s = atomicAdd(&g_q1cnt[qb], add);      // ONE global atomic per block
    }
    __syncthreads();

    const int base = base_s;
    const int n = (cnt < LBUF1) ? cnt : LBUF1;
    for (int i = tid; i < n; i += 256) {
        const int o = base + i;
        if (o < QCAP1) g_q1list[qb * QCAP1 + o] = buf[i];
    }
}

// ---------------------------------------------------------------------------
// KNN1 merge (unchanged from R14): sort <=1024 keys, first 32 = exact
// stable top-32. cnt<32 or cnt>QCAP1 -> fb list.
// ---------------------------------------------------------------------------
__global__ __launch_bounds__(256) void knn1_merge_kernel()
{
    __shared__ unsigned long long keys[QCAP1];   // 8 KB
    const int qb  = blockIdx.x;
    const int tid = threadIdx.x;
    const int cnt = g_q1cnt[qb];

    if (cnt < 32 || cnt > QCAP1) {
        if (tid == 0) {
            const int slot = atomicAdd(&g_fb1count, 1);
            g_fb1list[slot] = qb;
        }
        return;
    }

    for (int i = tid; i < QCAP1; i += 256)
        keys[i] = (i < cnt) ? g_q1list[qb * QCAP1 + i] : ~0ULL;
    __syncthreads();

    for (int k = 2; k <= QCAP1; k <<= 1) {
        for (int jj = k >> 1; jj > 0; jj >>= 1) {
            for (int idx = tid; idx < QCAP1 / 2; idx += 256) {
                const int i = ((idx & ~(jj - 1)) << 1) | (idx & (jj - 1));
                const int partner = i | jj;
                const bool asc = ((i & k) == 0);
                const unsigned long long a = keys[i];
                const unsigned long long c = keys[partner];
                if ((a > c) == asc) { keys[i] = c; keys[partner] = a; }
            }
            __syncthreads();
        }
    }

    if (tid < 32) {
        const int idx = (int)(keys[tid] & 0xFFFFFFFFull);
        g_fidx[qb * 32 + tid] = clampi(idx, 0, N_PTS - 1);
    }
}

// ---------------------------------------------------------------------------
// KNN1 exact fallback (unchanged): full scan + 2048-sort for flagged queries.
// ---------------------------------------------------------------------------
__global__ __launch_bounds__(256) void knn1_fb_kernel(
    const float* __restrict__ noisy)
{
    const int tid = threadIdx.x;
    const int count = g_fb1count;

    for (int qi = blockIdx.x; qi < count; qi += gridDim.x) {
        const int qb = g_fb1list[qi];
        const int b  = qb >> 7;
        const int p  = qb & 127;
        const float* nb = noisy + b * (N_PTS * 3);

        const int si = g_sidx[p];
        const float qx = nb[si * 3 + 0];
        const float qy = nb[si * 3 + 1];
        const float qz = nb[si * 3 + 2];

        float bd[8]; int bi[8];
#pragma unroll
        for (int i = 0; i < 8; ++i) { bd[i] = BIGF; bi[i] = 0x7fffffff; }

        for (int j = tid; j < N_PTS; j += 256) {
            const float dx = qx - nb[j * 3 + 0];
            const float dy = qy - nb[j * 3 + 1];
            const float dz = qz - nb[j * 3 + 2];
            const float d2 = fmaf(dz, dz, fmaf(dy, dy, dx * dx));
            if (d2 < bd[7]) {
                bd[7] = d2; bi[7] = j;
#pragma unroll
                for (int t = 7; t > 0; --t) {
                    if (bd[t] < bd[t - 1]) {
                        float td = bd[t]; bd[t] = bd[t - 1]; bd[t - 1] = td;
                        int   ti = bi[t]; bi[t] = bi[t - 1]; bi[t - 1] = ti;
                    }
                }
            }
        }

        __shared__ unsigned long long keys[2048];   // 16 KB
#pragma unroll
        for (int t = 0; t < 8; ++t) {
            keys[tid * 8 + t] = ((unsigned long long)__float_as_uint(bd[t]) << 32)
                              | (unsigned int)bi[t];
        }
        __syncthreads();

        for (int k = 2; k <= 2048; k <<= 1) {
            for (int jj = k >> 1; jj > 0; jj >>= 1) {
#pragma unroll
                for (int base = 0; base < 2048; base += 256) {
                    const int i = base + tid;
                    const int partner = i ^ jj;
                    if (partner > i) {
                        const bool asc = ((i & k) == 0);
                        const unsigned long long a = keys[i];
                        const unsigned long long c = keys[partner];
                        if ((a > c) == asc) { keys[i] = c; keys[partner] = a; }
                    }
                }
                __syncthreads();
            }
        }

        if (tid < 32) {
            const int idx = (int)(keys[tid] & 0xFFFFFFFFull);
            g_fidx[qb * 32 + tid] = clampi(idx, 0, N_PTS - 1);
        }
        __syncthreads();
    }
}

// ---------------------------------------------------------------------------
// KNN2 (unchanged from R13/R14): QPT=4, grid 8x125, tau-append lists.
// ---------------------------------------------------------------------------
__global__ __launch_bounds__(K2THR) void knn2_seg_kernel(
    const float* __restrict__ noisy,
    const float* __restrict__ clean)
{
    __shared__ float4 pts[SEGSZ];   // 5 KB
    const int tile = blockIdx.x;    // 0..7
    const int seg  = blockIdx.y;    // 0..124
    const int tid  = threadIdx.x;
    const int g0   = tile * (K2THR * QPT) + tid * QPT;
    const int b    = g0 >> 12;
    const float* cb = clean + b * (N_PTS * 3);
    const float* nb = noisy + b * (N_PTS * 3);

    const int base = seg * SEGSZ;
    for (int i = tid; i < SEGSZ; i += K2THR) {
        const int j = base + i;
        const float px = cb[j * 3 + 0], py = cb[j * 3 + 1], pz = cb[j * 3 + 2];
        const float pp = fmaf(pz, pz, fmaf(py, py, px * px));
        pts[i] = make_float4(px, py, pz, pp);
    }

    float fm2x[QPT], fm2y[QPT], fm2z[QPT];
    float bd0[QPT], bd1[QPT], bd2[QPT], bd3[QPT];
    int   bi0[QPT], bi1[QPT], bi2[QPT], bi3[QPT];
#pragma unroll
    for (int qq = 0; qq < QPT; ++qq) {
        const int fid = clampi(g_fidx[g0 + qq], 0, N_PTS - 1);
        const float fx = nb[fid * 3 + 0];
        const float fy = nb[fid * 3 + 1];
        const float fz = nb[fid * 3 + 2];
        fm2x[qq] = -2.0f * fx; fm2y[qq] = -2.0f * fy; fm2z[qq] = -2.0f * fz;
        const float ff = fmaf(fz, fz, fmaf(fy, fy, fx * fx));
        const float tau_p = TAU2 - ff;   // partial-space threshold
        bd0[qq] = tau_p; bd1[qq] = tau_p; bd2[qq] = tau_p; bd3[qq] = tau_p;
        bi0[qq] = -1;    bi1[qq] = -1;    bi2[qq] = -1;    bi3[qq] = -1;
    }

    __syncthreads();

#pragma unroll 2
    for (int j = 0; j < SEGSZ; ++j) {
        const float4 pp = pts[j];
#pragma unroll
        for (int qq = 0; qq < QPT; ++qq) {
            const float d2 = fmaf(fm2x[qq], pp.x, fmaf(fm2y[qq], pp.y, fmaf(fm2z[qq], pp.z, pp.w)));
            if (d2 < bd3[qq]) {
                bd3[qq] = d2; bi3[qq] = base + j;
                if (bd3[qq] < bd2[qq]) { float t = bd2[qq]; bd2[qq] = bd3[qq]; bd3[qq] = t; int ti = bi2[qq]; bi2[qq] = bi3[qq]; bi3[qq] = ti; }
                if (bd2[qq] < bd1[qq]) { float t = bd1[qq]; bd1[qq] = bd2[qq]; bd2[qq] = t; int ti = bi1[qq]; bi1[qq] = bi2[qq]; bi2[qq] = ti; }
                if (bd1[qq] < bd0[qq]) { float t = bd0[qq]; bd0[qq] = bd1[qq]; bd1[qq] = t; int ti = bi0[qq]; bi0[qq] = bi1[qq]; bi1[qq] = ti; }
            }
        }
    }

#pragma unroll
    for (int qq = 0; qq < QPT; ++qq) {
        const int g = g0 + qq;
        const float bds[4] = { bd0[qq], bd1[qq], bd2[qq], bd3[qq] };
        const int   bis[4] = { bi0[qq], bi1[qq], bi2[qq], bi3[qq] };
#pragma unroll
        for (int t = 0; t < 4; ++t) {
            if (bis[t] >= 0) {
                const int slot = atomicAdd(&g_qcnt[g], 1);
                if (slot < QCAP) g_qlist[(size_t)g * QCAP + slot] = make_float2(bds[t], __int_as_float(bis[t]));
            }
        }
    }
}

// ---------------------------------------------------------------------------
// Merge per-query knn2 list + epilogue (unchanged).
// ---------------------------------------------------------------------------
__global__ __launch_bounds__(128) void loss_kernel(
    const float* __restrict__ noisy,
    const float* __restrict__ clean)
{
    __shared__ float red[2];
    const int tid = threadIdx.x;
    const int g = blockIdx.x * 128 + tid;    // 64 blocks x 128
    const int b = g >> 12;
    const int p = (g >> 5) & 127;
    const float* nb = noisy + b * (N_PTS * 3);
    const float* cb = clean + b * (N_PTS * 3);

    const int si = g_sidx[p];
    const float qx = nb[si * 3 + 0], qy = nb[si * 3 + 1], qz = nb[si * 3 + 2];
    const int fid = clampi(g_fidx[g], 0, N_PTS - 1);
    const float fx = nb[fid * 3 + 0], fy = nb[fid * 3 + 1], fz = nb[fid * 3 + 2];

    const int cnt = g_qcnt[g];
    float t2 = 0.0f;

    if (cnt < 4 || cnt > QCAP) {
        const int slot = atomicAdd(&g_fcount, 1);
        g_flist[slot] = g;
    } else {
        float bd0 = BIGF, bd1 = BIGF, bd2 = BIGF, bd3 = BIGF;
        int   bi0 = 0x7fffffff, bi1 = 0x7fffffff, bi2 = 0x7fffffff, bi3 = 0x7fffffff;
        const float2* lst = g_qlist + (size_t)g * QCAP;
        for (int t = 0; t < cnt; ++t) {
            const float2 e = lst[t];
            const float d2 = e.x;
            const int  idx = __float_as_int(e.y);
            if (d2 < bd3 || (d2 == bd3 && idx < bi3)) {
                bd3 = d2; bi3 = idx;
                if (bd3 < bd2 || (bd3 == bd2 && bi3 < bi2)) { float q0 = bd2; bd2 = bd3; bd3 = q0; int ti = bi2; bi2 = bi3; bi3 = ti; }
                if (bd2 < bd1 || (bd2 == bd1 && bi2 < bi1)) { float q0 = bd1; bd1 = bd2; bd2 = q0; int ti = bi1; bi1 = bi2; bi2 = ti; }
                if (bd1 < bd0 || (bd1 == bd0 && bi1 < bi0)) { float q0 = bd0; bd0 = bd1; bd1 = q0; int ti = bi0; bi0 = bi1; bi1 = ti; }
            }
        }

        const float mx = 0.25f * (cb[bi0*3+0] + cb[bi1*3+0] + cb[bi2*3+0] + cb[bi3*3+0]);
        const float my = 0.25f * (cb[bi0*3+1] + cb[bi1*3+1] + cb[bi2*3+1] + cb[bi3*3+1]);
        const float mz = 0.25f * (cb[bi0*3+2] + cb[bi1*3+2] + cb[bi2*3+2] + cb[bi3*3+2]);

        const float gx = mx - fx, gy = my - fy, gz = mz - fz;
        const float rx = fx - qx, ry = fy - qy, rz = fz - qz;
        const float ex = rx * g_WxS[0] + ry * g_WxS[3] + rz * g_WxS[6] + qx * g_M3[0] + qy * g_M3[3] + qz * g_M3[6];
        const float ey = rx * g_WxS[1] + ry * g_WxS[4] + rz * g_WxS[7] + qx * g_M3[1] + qy * g_M3[4] + qz * g_M3[7];
        const float ez = rx * g_WxS[2] + ry * g_WxS[5] + rz * g_WxS[8] + qx * g_M3[2] + qy * g_M3[5] + qz * g_M3[8];
        const float dx = ex - gx, dy = ey - gy, dz = ez - gz;
        t2 = dx * dx + dy * dy + dz * dz;
    }

#pragma unroll
    for (int off = 32; off; off >>= 1) t2 += __shfl_down(t2, off);
    if ((tid & 63) == 0) red[tid >> 6] = t2;
    __syncthreads();
    if (tid == 0) g_lpart[blockIdx.x] = red[0] + red[1];
}

// ---------------------------------------------------------------------------
// KNN2 exact fallback (unchanged).
// ---------------------------------------------------------------------------
__global__ __launch_bounds__(64) void fallback_kernel(
    const float* __restrict__ noisy,
    const float* __restrict__ clean)
{
    const int lane  = threadIdx.x;
    const int count = g_fcount;

    for (int qi = blockIdx.x; qi < count; qi += gridDim.x) {
        const int g = g_flist[qi];
        const int b = g >> 12;
        const int p = (g >> 5) & 127;
        const float* nb = noisy + b * (N_PTS * 3);
        const float* cb = clean + b * (N_PTS * 3);

        const int fid = clampi(g_fidx[g], 0, N_PTS - 1);
        const float fx = nb[fid * 3 + 0], fy = nb[fid * 3 + 1], fz = nb[fid * 3 + 2];

        float bd[4]; int bi[4];
#pragma unroll
        for (int t = 0; t < 4; ++t) { bd[t] = BIGF; bi[t] = 0x7fffffff; }

        for (int j = lane; j < N_PTS; j += 64) {
            const float dx = fx - cb[j * 3 + 0];
            const float dy = fy - cb[j * 3 + 1];
            const float dz = fz - cb[j * 3 + 2];
            const float d2 = fmaf(dz, dz, fmaf(dy, dy, dx * dx));
            if (d2 < bd[3]) {
                bd[3] = d2; bi[3] = j;
#pragma unroll
                for (int t = 3; t > 0; --t) {
                    if (bd[t] < bd[t - 1]) {
                        float td = bd[t]; bd[t] = bd[t - 1]; bd[t - 1] = td;
                        int   ti = bi[t]; bi[t] = bi[t - 1]; bi[t - 1] = ti;
                    }
                }
            }
        }

        int nn[4];
        int cur = 0;
        for (int r = 0; r < 4; ++r) {
            float v  = (cur < 4) ? bd[cur] : BIGF;
            int   vi = (cur < 4) ? bi[cur] : 0x7fffffff;
            int   who = lane;
#pragma unroll
            for (int off = 32; off; off >>= 1) {
                const float v2  = __shfl_down(v, off);
                const int   vi2 = __shfl_down(vi, off);
                const int   w2  = __shfl_down(who, off);
                if (v2 < v || (v2 == v && vi2 < vi)) { v = v2; vi = vi2; who = w2; }
            }
            const int bvi = __shfl(vi, 0);
            const int bwh = __shfl(who, 0);
            nn[r] = bvi;
            if (lane == bwh) cur++;
        }

        if (lane == 0) {
            const int si = g_sidx[p];
            const float qx = nb[si * 3 + 0], qy = nb[si * 3 + 1], qz = nb[si * 3 + 2];
            const int n0 = clampi(nn[0],0,N_PTS-1), n1 = clampi(nn[1],0,N_PTS-1);
            const int n2 = clampi(nn[2],0,N_PTS-1), n3 = clampi(nn[3],0,N_PTS-1);
            const float mx = 0.25f * (cb[n0*3+0] + cb[n1*3+0] + cb[n2*3+0] + cb[n3*3+0]);
            const float my = 0.25f * (cb[n0*3+1] + cb[n1*3+1] + cb[n2*3+1] + cb[n3*3+1]);
            const float mz = 0.25f * (cb[n0*3+2] + cb[n1*3+2] + cb[n2*3+2] + cb[n3*3+2]);
            const float gx = mx - fx, gy = my - fy, gz = mz - fz;
            const float rx = fx - qx, ry = fy - qy, rz = fz - qz;
            const float ex = rx * g_WxS[0] + ry * g_WxS[3] + rz * g_WxS[6] + qx * g_M3[0] + qy * g_M3[3] + qz * g_M3[6];
            const float ey = rx * g_WxS[1] + ry * g_WxS[4] + rz * g_WxS[7] + qx * g_M3[1] + qy * g_M3[4] + qz * g_M3[7];
            const float ez = rx * g_WxS[2] + ry * g_WxS[5] + rz * g_WxS[8] + qx * g_M3[2] + qy * g_M3[5] + qz * g_M3[8];
            const float dx = ex - gx, dy = ey - gy, dz = ez - gz;
            atomicAdd(&g_lpart[128 + blockIdx.x], dx * dx + dy * dy + dz * dz);
        }
    }
}

__global__ void final_kernel(float* __restrict__ out)
{
    const int tid = threadIdx.x;    // 64
    float v = (g_lpart[tid] + g_lpart[64 + tid]) + (g_lpart[128 + tid] + g_lpart[192 + tid]);
#pragma unroll
    for (int off = 32; off; off >>= 1) v += __shfl_down(v, off);
    if (tid == 0) out[0] = v * (50.0f / 8192.0f);   // 0.5 * (1/SIGMA) / 8192
}

extern "C" void kernel_launch(void* const* d_in, const int* in_sizes, int n_in,
                              void* d_out, int out_size, void* d_ws, size_t ws_size,
                              hipStream_t stream)
{
    (void)d_ws; (void)ws_size; (void)in_sizes; (void)n_in; (void)out_size;

    const float* noisy = (const float*)d_in[0];
    const float* clean = (const float*)d_in[1];
    const float* Wf    = (const float*)d_in[3];
    const float* Wx    = (const float*)d_in[4];
    const float* Wc    = (const float*)d_in[5];

    prep_kernel<<<1, 128, 0, stream>>>(d_in[2], Wf, Wx, Wc);
    knn1_scan_kernel<<<dim3(256, K1SUB), 256, 0, stream>>>(noisy);
    knn1_merge_kernel<<<256, 256, 0, stream>>>();
    knn1_fb_kernel<<<64, 256, 0, stream>>>(noisy);
    knn2_seg_kernel<<<dim3(K2TILES, NSEG), K2THR, 0, stream>>>(noisy, clean);
    loss_kernel<<<64, 128, 0, stream>>>(noisy, clean);
    fallback_kernel<<<32, 64, 0, stream>>>(noisy, clean);
    final_kernel<<<1, 64, 0, stream>>>((float*)d_out);
}